// Round 5
// baseline (136.153 us; speedup 1.0000x reference)
//
#include <hip/hip_runtime.h>
#include <math.h>

// RandomLowRes2D: per-image Gaussian blur (R=15, symmetric pad) + linear
// down/up resample along a per-image runtime axis.
//
// Fusion: low[j] = (1-fr)*s[la] + fr*s[la+1] collapses blur+downsample into a
// single fused filter on img: cw[k] = fma(fr, dwe[k], we[k+1]),
// dwe[k] = we[k] - we[k+1].
//
// Round 5: ax0 was a serial dependent chain (one compute_low per output row,
// gated by a branch). Restructure ax0 into the same two-phase parallel shape
// as ax1: phase 1 computes ALL lows the segment needs (mlow <= 10 for res>=1,
// SEG0=8) as independent (j, col4) items — float4 loads, deep ILP; phase 2
// upsamples from LDS (ds_read_b128, conflict-free) + coalesced float4 stores.

#define RR 15
#define TAPS 31
#define SEG0 8                   // ax0: output rows per block (64 blocks/img)
#define MAXJ 10                  // max lows per ax0 segment (res >= 1)
#define SIG_PER_FWHM 0.42466090014400953f  // 1/sqrt(8 ln 2)

__global__ __launch_bounds__(256) void lowres2d_kernel(
    const float* __restrict__ x,
    const float* __restrict__ resolution,
    const int*   __restrict__ axis,
    const float* __restrict__ gap,
    float* __restrict__ out)
{
    const int tid = threadIdx.x;
    const int n   = blockIdx.y;          // image index
    const int bx  = blockIdx.x;          // 0..127

    const float res = resolution[n];
    const int   ax  = axis[n];
    const float gp  = gap[n];

    // ax0 images use 64 blocks of SEG0=8 rows; rest exit (block-uniform)
    if (ax == 0 && bx >= 64) return;

    const float sig = fmaxf(res * gp * SIG_PER_FWHM, 1e-6f);
    int n_low = (int)floorf(512.0f / res);
    if (n_low < 1) n_low = 1;
    if (n_low > 512) n_low = 512;
    const float nlm1f = (float)(n_low - 1);

    // adaptive radius: normalized weights < 1e-6 outside +-kr (sum >= 1)
    int kr = (int)(sig * 5.2565f) + 1;
    if (kr > RR) kr = RR;
    const int k0 = RR - kr, k1 = RR + 1 + kr;   // fused window k in [k0, k1]
    const int la_lo = kr, la_hi = 510 - kr;     // interior: no reflect needed

    // we[0]=0, we[1..31]=normalized gaussian, we[32]=0; dwe[k]=we[k]-we[k+1]
    __shared__ float we[34];
    __shared__ float dwe[32];
    // union scratch: ax0 -> lows [MAXJ][512]; ax1 -> img 4x520 + low 4x516
    __shared__ float smem[MAXJ * 512];

    if (tid < 32) {
        const int k = tid;
        float r = 0.0f;
        if (k < TAPS) {
            float d = (float)(k - RR) / sig;
            r = expf(-0.5f * d * d);
        }
        float tot = r;
        tot += __shfl_xor(tot, 1, 32);
        tot += __shfl_xor(tot, 2, 32);
        tot += __shfl_xor(tot, 4, 32);
        tot += __shfl_xor(tot, 8, 32);
        tot += __shfl_xor(tot, 16, 32);
        float rm1 = __shfl_up(r, 1, 32);
        if (k == 0) rm1 = 0.0f;
        const float inv = 1.0f / tot;            // tot >= 1 (center tap)
        we[k + 1] = r * inv;                     // lane31 writes we[32]=0
        if (k == 0) we[0] = 0.0f;
        dwe[k] = (rm1 - r) * inv;
    }
    __syncthreads();

    const size_t base = (size_t)n * (512 * 512);
    const float* img = x + base;
    float* o = out + base;

    if (ax == 0) {
        // ------- ax0: two-phase, fully parallel, float4 throughout --------
        const int i0 = bx * SEG0;
        const float4* img4 = (const float4*)img;

        // low index range needed by rows i0..i0+7 (computed with the exact
        // same float ops as phase 2 so floor decisions agree)
        int jA = (int)floorf(fminf((float)i0 / res, nlm1f));
        if (jA > n_low - 1) jA = n_low - 1;
        int jL = (int)floorf(fminf((float)(i0 + SEG0 - 1) / res, nlm1f));
        if (jL > n_low - 1) jL = n_low - 1;
        int jB = (jL + 1 < n_low) ? (jL + 1) : (n_low - 1);
        const int mlow = jB - jA + 1;            // <= MAXJ

        // phase 1: lows, (c4, jj)-parallel, independent items
        for (int it = tid; it < mlow * 128; it += 256) {
            const int c4 = it & 127;
            const int jj = it >> 7;
            const int j  = jA + jj;
            float pos = fminf((float)j * res, 511.0f);
            float lof = floorf(pos);
            float fr  = pos - lof;
            int   la  = (int)lof;
            float4 acc = make_float4(0.0f, 0.0f, 0.0f, 0.0f);
            if (la >= la_lo && la <= la_hi) {
                for (int k = k0; k <= k1; ++k) {
                    int t = la - RR + k;
                    float cw = fmaf(fr, dwe[k], we[k + 1]);
                    float4 v = img4[(size_t)(t * 128 + c4)];
                    acc.x = fmaf(cw, v.x, acc.x);
                    acc.y = fmaf(cw, v.y, acc.y);
                    acc.z = fmaf(cw, v.z, acc.z);
                    acc.w = fmaf(cw, v.w, acc.w);
                }
            } else {
                for (int k = k0; k <= k1; ++k) {
                    int t = la - RR + k;
                    t = (t < 0)   ? (-1 - t)   : t;  // symmetric reflect
                    t = (t > 511) ? (1023 - t) : t;
                    float cw = fmaf(fr, dwe[k], we[k + 1]);
                    float4 v = img4[(size_t)(t * 128 + c4)];
                    acc.x = fmaf(cw, v.x, acc.x);
                    acc.y = fmaf(cw, v.y, acc.y);
                    acc.z = fmaf(cw, v.z, acc.z);
                    acc.w = fmaf(cw, v.w, acc.w);
                }
            }
            ((float4*)(smem + jj * 512))[c4] = acc;
        }
        __syncthreads();

        // phase 2: upsample, (half, c4) threads x 4 rows, coalesced stores
        {
            const int c4   = tid & 127;
            const int half = tid >> 7;
            float4* out4 = (float4*)o;
            #pragma unroll
            for (int q = 0; q < 4; ++q) {
                const int i = i0 + half * 4 + q;
                float pos2 = fminf((float)i / res, nlm1f);  // exact IEEE div
                float l2f  = floorf(pos2);
                float fr2  = pos2 - l2f;
                int lo2 = (int)l2f;
                if (lo2 > n_low - 1) lo2 = n_low - 1;
                int hi2 = (lo2 + 1 < n_low) ? (lo2 + 1) : (n_low - 1);
                float4 a = ((const float4*)(smem + (lo2 - jA) * 512))[c4];
                float4 b = ((const float4*)(smem + (hi2 - jA) * 512))[c4];
                float om = 1.0f - fr2;
                float4 ov;
                ov.x = a.x * om + b.x * fr2;
                ov.y = a.y * om + b.y * fr2;
                ov.z = a.z * om + b.z * fr2;
                ov.w = a.w * om + b.w * fr2;
                out4[(size_t)(i * 128 + c4)] = ov;
            }
        }
    } else {
        // ---------------- ax1: LDS-tiled 4 rows, coalesced ----------------
        const int h0 = bx * 4;
        float* s_img = smem;               // 4 rows, stride 520
        float* s_low = smem + 4 * 520;     // 4 rows, stride 516

        // load 4x512 tile, float4 coalesced (512 float4 over 256 threads)
        const float4* img4 = (const float4*)(img + (size_t)h0 * 512);
        #pragma unroll
        for (int p = 0; p < 2; ++p) {
            int m = p * 256 + tid;
            int r = m >> 7, c4 = m & 127;
            ((float4*)(s_img + r * 520))[c4] = img4[r * 128 + c4];
        }
        __syncthreads();

        // compute lows: one wave per row (r uniform per wave), j strided 64
        {
            const int r = tid >> 6;
            const float* srow = s_img + r * 520;
            for (int j = (tid & 63); j < n_low; j += 64) {
                float pos = fminf((float)j * res, 511.0f);
                float lof = floorf(pos);
                float fr  = pos - lof;
                int   la  = (int)lof;
                float acc = 0.0f;
                if (la >= la_lo && la <= la_hi) {
                    #pragma unroll 4
                    for (int k = k0; k <= k1; ++k) {
                        int t = la - RR + k;
                        float cw = fmaf(fr, dwe[k], we[k + 1]);
                        acc = fmaf(cw, srow[t], acc);
                    }
                } else {
                    for (int k = k0; k <= k1; ++k) {
                        int t = la - RR + k;
                        t = (t < 0)   ? (-1 - t)   : t;
                        t = (t > 511) ? (1023 - t) : t;
                        float cw = fmaf(fr, dwe[k], we[k + 1]);
                        acc = fmaf(cw, srow[t], acc);
                    }
                }
                s_low[r * 516 + j] = acc;
            }
        }
        __syncthreads();

        // upsample + coalesced float4 stores
        float4* out4 = (float4*)(o + (size_t)h0 * 512);
        #pragma unroll
        for (int p = 0; p < 2; ++p) {
            int m = p * 256 + tid;
            int r = m >> 7, c4 = m & 127;
            const float* lrow = s_low + r * 516;
            float vals[4];
            #pragma unroll
            for (int q = 0; q < 4; ++q) {
                int i = c4 * 4 + q;
                float pos2 = fminf((float)i / res, nlm1f);
                float l2f  = floorf(pos2);
                float fr2  = pos2 - l2f;
                int lo2 = (int)l2f;
                if (lo2 > n_low - 1) lo2 = n_low - 1;
                int hi2 = (lo2 + 1 < n_low) ? (lo2 + 1) : (n_low - 1);
                vals[q] = lrow[lo2] * (1.0f - fr2) + lrow[hi2] * fr2;
            }
            float4 ov;
            ov.x = vals[0]; ov.y = vals[1]; ov.z = vals[2]; ov.w = vals[3];
            out4[r * 128 + c4] = ov;
        }
    }
}

extern "C" void kernel_launch(void* const* d_in, const int* in_sizes, int n_in,
                              void* d_out, int out_size, void* d_ws, size_t ws_size,
                              hipStream_t stream) {
    const float* x          = (const float*)d_in[0];
    const float* resolution = (const float*)d_in[1];
    const int*   axis       = (const int*)d_in[2];
    const float* gap        = (const float*)d_in[3];
    float* out = (float*)d_out;

    const int n_img = in_sizes[1];   // B*C = 64

    dim3 grid(128, n_img);
    lowres2d_kernel<<<grid, 256, 0, stream>>>(x, resolution, axis, gap, out);
}